// Round 11
// baseline (5002.302 us; speedup 1.0000x reference)
//
#include <hip/hip_runtime.h>

typedef _Float16 f16;
typedef _Float16 f16x8 __attribute__((ext_vector_type(8)));
typedef float f32x4 __attribute__((ext_vector_type(4)));
typedef unsigned long long u64;

#define B_ 64
#define S_ 1024
#define E_ 256
#define H_ 512
#define NG 1536         // 3*H packed gate rows (r | z | n)
#define TCH 128         // timesteps per chunk
#define NCHUNK (S_/TCH)
#define ROWS_CH (TCH*B_)   // 8192
#define HS_LD 544       // h LDS row stride (f16): quad-bank 4*bq+j4 distinct for MFMA reads

__device__ __forceinline__ float sigm(float x) { return 1.f / (1.f + __expf(-x)); }

#define ALOAD(p) __hip_atomic_load((p), __ATOMIC_RELAXED, __HIP_MEMORY_SCOPE_AGENT)
#define ASTORE(p, v) __hip_atomic_store((p), (v), __ATOMIC_RELAXED, __HIP_MEMORY_SCOPE_AGENT)

// ---------------- embedding gather -> fp16, rows ordered (t, b) ----------------
__global__ __launch_bounds__(256) void k_embed(const int* __restrict__ tok,
        const float* __restrict__ emb, f16* __restrict__ X, int t0) {
    int idx = blockIdx.x * 256 + threadIdx.x;     // ROWS_CH * (E_/4) units
    int r = idx >> 6;                             // chunk-local row
    int c4 = (idx & 63) << 2;
    int t = t0 + (r >> 6), b = r & 63;
    int tk = tok[b * S_ + t];
    float4 v = *reinterpret_cast<const float4*>(emb + (size_t)tk * E_ + c4);
    union { f16 h[4]; u64 u; } w;
    w.h[0] = (f16)v.x; w.h[1] = (f16)v.y; w.h[2] = (f16)v.z; w.h[3] = (f16)v.w;
    *reinterpret_cast<u64*>(X + (size_t)r * E_ + c4) = w.u;
}

// ------------- pack [gate_w slice ; gi_or_gh_w] into fp16 [1536][KK] -------------
__global__ __launch_bounds__(256) void k_packW(const float* __restrict__ gw, int ld, int off,
        const float* __restrict__ g2, f16* __restrict__ W, int KK) {
    int idx = blockIdx.x * 256 + threadIdx.x;
    int per = KK >> 2;
    if (idx >= NG * per) return;
    int row = idx / per;
    int c4 = (idx % per) << 2;
    const float* src = (row < 1024) ? gw + (size_t)row * ld + off + c4
                                    : g2 + (size_t)(row - 1024) * KK + c4;
    float4 v = *reinterpret_cast<const float4*>(src);
    union { f16 h[4]; u64 u; } w;
    w.h[0] = (f16)v.x; w.h[1] = (f16)v.y; w.h[2] = (f16)v.z; w.h[3] = (f16)v.w;
    *reinterpret_cast<u64*>(W + (size_t)row * KK + c4) = w.u;
}

__global__ __launch_bounds__(256) void k_packBias(const float* __restrict__ gb,
        const float* __restrict__ gib, float* __restrict__ bias) {
    int i = blockIdx.x * 256 + threadIdx.x;
    if (i < 1024) bias[i] = gb[i];
    else if (i < NG) bias[i] = gib[i - 1024];
}

// --------- GEMM: C[M,1536] = A[M,K] * Bm[1536,K]^T + bias ; fp16 in/out, fp32 acc ---------
__global__ __launch_bounds__(256) void k_gemm(const f16* __restrict__ A,
        const f16* __restrict__ Bm, const float* __restrict__ bias,
        f16* __restrict__ C, int K) {
    __shared__ f16 As[64][40];
    __shared__ f16 Bs[64][40];
    const int tid = threadIdx.x;
    const int m0 = blockIdx.y << 6, n0 = blockIdx.x << 6;
    const int w = tid >> 6, l = tid & 63;
    const int wr = (w >> 1) << 5, wc = (w & 1) << 5;
    const int srow = tid >> 2, sc8 = (tid & 3) << 3;
    const int fr = l & 15, kl = (l >> 4) << 3;
    f32x4 acc[2][2] = {};
    for (int k0 = 0; k0 < K; k0 += 32) {
        *reinterpret_cast<f16x8*>(&As[srow][sc8]) =
            *reinterpret_cast<const f16x8*>(A + (size_t)(m0 + srow) * K + k0 + sc8);
        *reinterpret_cast<f16x8*>(&Bs[srow][sc8]) =
            *reinterpret_cast<const f16x8*>(Bm + (size_t)(n0 + srow) * K + k0 + sc8);
        __syncthreads();
        f16x8 a0 = *reinterpret_cast<const f16x8*>(&As[wr + fr][kl]);
        f16x8 a1 = *reinterpret_cast<const f16x8*>(&As[wr + 16 + fr][kl]);
        f16x8 b0 = *reinterpret_cast<const f16x8*>(&Bs[wc + fr][kl]);
        f16x8 b1 = *reinterpret_cast<const f16x8*>(&Bs[wc + 16 + fr][kl]);
        acc[0][0] = __builtin_amdgcn_mfma_f32_16x16x32_f16(a0, b0, acc[0][0], 0, 0, 0);
        acc[0][1] = __builtin_amdgcn_mfma_f32_16x16x32_f16(a0, b1, acc[0][1], 0, 0, 0);
        acc[1][0] = __builtin_amdgcn_mfma_f32_16x16x32_f16(a1, b0, acc[1][0], 0, 0, 0);
        acc[1][1] = __builtin_amdgcn_mfma_f32_16x16x32_f16(a1, b1, acc[1][1], 0, 0, 0);
        __syncthreads();
    }
    for (int fm = 0; fm < 2; ++fm)
        for (int fn = 0; fn < 2; ++fn) {
            int col = n0 + wc + (fn << 4) + fr;
            float bv = bias[col];
            for (int j = 0; j < 4; ++j) {
                int rowg = m0 + wr + (fm << 4) + ((l >> 4) << 2) + j;
                C[(size_t)rowg * NG + col] = (f16)(acc[fm][fn][j] + bv);
            }
        }
}

// ----------- persistent GRU recurrence: MFMA, tag-granules, 1 barrier/step -----------
// 256 WGs x 256 thr (1/CU). c=blk&7 (cluster of 8 batches), l=(blk>>3)&1, gg=blk>>4:
// WG owns 32 outputs. Wave = 2 MFMA tiles (A-rows = 4 outputs x {r,z,n_h,pad}).
// Exchange: tag-in-data u64 granules (tag<<32 | hB<<16 | hA), relaxed agent atomics.
// Granule = outputs (o, o+4) of ONE batch from ONE lane -> computing lanes publish
// directly (no hx gather, no second barrier). Consumer: round-based batched retry
// (re-issue ALL stale granules per round -> ~1 LLC latency per round, not 8 chained).
// HS double-buffered -> single __syncthreads per step. Z software-pipelined (s+1
// loaded during step s). Ring-4 reuse race-free as in R9.
__global__ __launch_bounds__(256, 1) void k_recur5(
        const f16* __restrict__ Wh0p, const f16* __restrict__ Wh1p,
        const f16* __restrict__ Z0, const f16* __restrict__ Z1,
        const float* __restrict__ ghb0, const float* __restrict__ ghb1,
        u64* ring0, u64* ring1, f16* __restrict__ H0out, f16* __restrict__ h1out,
        int t00, int n0, int t01, int n1) {
    __shared__ __align__(16) f16 HS[2][8][HS_LD];   // double-buffered staged h(s)
    const int blk = blockIdx.x;
    const int c = blk & 7;
    const int l = (blk >> 3) & 1;
    const int gg = blk >> 4;                      // 0..15
    const int nsteps = l ? n1 : n0;
    if (nsteps <= 0) return;
    const int t0 = l ? t01 : t00;
    const f16* __restrict__ Wh = l ? Wh1p : Wh0p;
    const f16* __restrict__ Z  = l ? Z1 : Z0;
    const float* __restrict__ ghb = l ? ghb1 : ghb0;
    u64* ring = l ? ring1 : ring0;                // [4 slots][8 clusters][2048 granules]

    const int i0 = gg << 5;                       // WG's first output
    const int tid = threadIdx.x;
    const int w = tid >> 6;                       // wave -> outputs i0+8w..+8w+7
    const int lane = tid & 63;
    const int colb = lane & 15;                   // C/D col (batch slot; 8-15 dup)
    const int bq = lane & 7;                      // real batch within cluster
    const int j4 = lane >> 4;                     // k-octet for A/B frags; out-group for C/D
    const int rrow = lane & 15;
    const int ol = rrow >> 2, gate = rrow & 3;    // A-row decode: row = ol*4 + gate (3=pad)

    // ---- preload recurrent weights into registers (constant all steps) ----
    f16x8 wA[2][16];
    #pragma unroll
    for (int tl = 0; tl < 2; ++tl) {
        const int out = i0 + (w << 3) + (tl << 2) + ol;
        #pragma unroll
        for (int t = 0; t < 16; ++t) {
            f16x8 v{};
            if (gate < 3)
                v = *reinterpret_cast<const f16x8*>(
                        Wh + ((size_t)(gate * H_ + out)) * H_ + (t << 5) + (j4 << 3));
            wA[tl][t] = v;
        }
    }
    const int outA = i0 + (w << 3) + j4;          // tile 0 gate-math output
    const int outB = outA + 4;                    // tile 1
    const float gbA = ghb[outA], gbB = ghb[outB];

    // ---- Z(0) prologue load (software pipeline registers) ----
    float zrA, zzA, znA, zrB, zzB, znB;
    {
        const size_t zrow = ((size_t)(c << 3) + bq) * NG;
        zrA = (float)Z[zrow + outA]; zzA = (float)Z[zrow + H_ + outA];
        znA = (float)Z[zrow + 2 * H_ + outA];
        zrB = (float)Z[zrow + outB]; zzB = (float)Z[zrow + H_ + outB];
        znB = (float)Z[zrow + 2 * H_ + outB];
    }

    for (int sl = 0; sl < nsteps; ++sl) {
        const int s = t0 + sl;
        f16* Hc = &HS[sl & 1][0][0];
        // ---- stage h(s): 8 granules/thread, round-based batched retry ----
        {
            const u64* src = ring + ((size_t)(s & 3) * 8 + c) * 2048;
            u64 g[8];
            #pragma unroll
            for (int i = 0; i < 8; ++i) g[i] = ALOAD(src + (i << 8) + tid);
            unsigned miss = 0;
            #pragma unroll
            for (int i = 0; i < 8; ++i) {
                if ((unsigned)(g[i] >> 32) == (unsigned)s) {
                    const int rest = tid, b = i;
                    const int og = ((rest >> 4) << 5) + (((rest >> 2) & 3) << 3) + (rest & 3);
                    Hc[b * HS_LD + og]     = __builtin_bit_cast(f16, (unsigned short)(g[i] & 0xffff));
                    Hc[b * HS_LD + og + 4] = __builtin_bit_cast(f16, (unsigned short)((g[i] >> 16) & 0xffff));
                } else miss |= 1u << i;
            }
            while (miss) {
                #pragma unroll
                for (int i = 0; i < 8; ++i)
                    if (miss & (1u << i)) g[i] = ALOAD(src + (i << 8) + tid);
                #pragma unroll
                for (int i = 0; i < 8; ++i)
                    if ((miss & (1u << i)) && (unsigned)(g[i] >> 32) == (unsigned)s) {
                        const int rest = tid, b = i;
                        const int og = ((rest >> 4) << 5) + (((rest >> 2) & 3) << 3) + (rest & 3);
                        Hc[b * HS_LD + og]     = __builtin_bit_cast(f16, (unsigned short)(g[i] & 0xffff));
                        Hc[b * HS_LD + og + 4] = __builtin_bit_cast(f16, (unsigned short)((g[i] >> 16) & 0xffff));
                        miss &= ~(1u << i);
                    }
            }
        }
        __syncthreads();                          // the ONLY barrier per step
        // ---- Z(sl+1) prefetch (independent; hides under MFMA) ----
        float nrA = 0, nzA = 0, nnA = 0, nrB = 0, nzB = 0, nnB = 0;
        if (sl + 1 < nsteps) {
            const size_t zrow = ((size_t)(sl + 1) * 64 + (c << 3) + bq) * NG;
            nrA = (float)Z[zrow + outA]; nzA = (float)Z[zrow + H_ + outA];
            nnA = (float)Z[zrow + 2 * H_ + outA];
            nrB = (float)Z[zrow + outB]; nzB = (float)Z[zrow + H_ + outB];
            nnB = (float)Z[zrow + 2 * H_ + outB];
        }
        // ---- MFMA: 2 tiles x K=512 (16 k-steps), B-frag shared across tiles ----
        f32x4 a00{}, a01{}, a10{}, a11{};
        #pragma unroll
        for (int t = 0; t < 16; ++t) {
            f16x8 bf = *reinterpret_cast<const f16x8*>(&Hc[bq * HS_LD + (t << 5) + (j4 << 3)]);
            if (t & 1) {
                a01 = __builtin_amdgcn_mfma_f32_16x16x32_f16(wA[0][t], bf, a01, 0, 0, 0);
                a11 = __builtin_amdgcn_mfma_f32_16x16x32_f16(wA[1][t], bf, a11, 0, 0, 0);
            } else {
                a00 = __builtin_amdgcn_mfma_f32_16x16x32_f16(wA[0][t], bf, a00, 0, 0, 0);
                a10 = __builtin_amdgcn_mfma_f32_16x16x32_f16(wA[1][t], bf, a10, 0, 0, 0);
            }
        }
        f32x4 dA = a00 + a01;                     // rows: outA {r, z, n_h, pad}
        f32x4 dB = a10 + a11;                     // rows: outB
        // ---- gate math + direct tagged publish (no gather, no second barrier) ----
        if (colb < 8) {
            float holdA = (float)Hc[bq * HS_LD + outA];
            float holdB = (float)Hc[bq * HS_LD + outB];
            float rA = sigm(zrA + dA[0]);
            float zA = sigm(zzA + dA[1]);
            float nA = tanhf(znA + rA * (dA[2] + gbA));
            float rB = sigm(zrB + dB[0]);
            float zB = sigm(zzB + dB[1]);
            float nB = tanhf(znB + rB * (dB[2] + gbB));
            f16 hA = (f16)((1.f - zA) * nA + zA * holdA);
            f16 hB = (f16)((1.f - zB) * nB + zB * holdB);
            unsigned short uA = __builtin_bit_cast(unsigned short, hA);
            unsigned short uB = __builtin_bit_cast(unsigned short, hB);
            u64 gr = ((u64)(unsigned)(s + 1) << 32) | ((u64)uB << 16) | (u64)uA;
            const size_t gi = ((size_t)bq << 8) + (gg << 4) + (w << 2) + j4;
            ASTORE(ring + ((size_t)((s + 1) & 3) * 8 + c) * 2048 + gi, gr);
            if (l == 0) {
                f16* hp = H0out + ((size_t)sl * 64 + (c << 3) + bq) * H_;
                hp[outA] = hA; hp[outB] = hB;
            } else if (s == S_ - 1) {
                f16* hp = h1out + ((size_t)(c << 3) + bq) * H_;
                hp[outA] = hA; hp[outB] = hB;
            }
        }
        // rotate Z pipeline registers
        zrA = nrA; zzA = nzA; znA = nnA; zrB = nrB; zzB = nzB; znB = nnB;
    }
}

// ------------------------------- final head -------------------------------
__global__ __launch_bounds__(64) void k_final(const f16* __restrict__ h,
        const float* __restrict__ fcw, const float* __restrict__ fcb,
        float* __restrict__ out) {
    int b = threadIdx.x;
    float acc = fcb[0];
    for (int k = 0; k < H_; ++k) acc += (float)h[(size_t)b * H_ + k] * fcw[k];
    out[b] = sigm(acc);
}

extern "C" void kernel_launch(void* const* d_in, const int* in_sizes, int n_in,
                              void* d_out, int out_size, void* d_ws, size_t ws_size,
                              hipStream_t stream) {
    (void)in_sizes; (void)n_in; (void)out_size; (void)ws_size;
    const int*   tokens = (const int*)d_in[0];
    const float* emb  = (const float*)d_in[1];
    const float* fc_w = (const float*)d_in[2];
    const float* fc_b = (const float*)d_in[3];
    const float* gw0  = (const float*)d_in[4];
    const float* gb0  = (const float*)d_in[5];
    const float* giw0 = (const float*)d_in[6];
    const float* gib0 = (const float*)d_in[7];
    const float* ghw0 = (const float*)d_in[8];
    const float* ghb0 = (const float*)d_in[9];
    const float* gw1  = (const float*)d_in[10];
    const float* gb1  = (const float*)d_in[11];
    const float* giw1 = (const float*)d_in[12];
    const float* gib1 = (const float*)d_in[13];
    const float* ghw1 = (const float*)d_in[14];
    const float* ghb1 = (const float*)d_in[15];

    char* base = (char*)d_ws;
    size_t off = 0;
    auto carve = [&](size_t bytes) {
        char* p = base + off;
        off = (off + bytes + 255) & ~(size_t)255;
        return p;
    };
    f16*   Wx0   = (f16*)carve((size_t)NG * 256 * 2);
    f16*   Wh0   = (f16*)carve((size_t)NG * 512 * 2);
    f16*   Wx1   = (f16*)carve((size_t)NG * 512 * 2);
    f16*   Wh1   = (f16*)carve((size_t)NG * 512 * 2);
    float* bias0 = (float*)carve(NG * 4);
    float* bias1 = (float*)carve(NG * 4);
    u64*   ring0 = (u64*)carve((size_t)4 * 8 * 2048 * 8);     // 512 KB
    u64*   ring1 = (u64*)carve((size_t)4 * 8 * 2048 * 8);     // 512 KB
    f16*   h1out = (f16*)carve((size_t)B_ * H_ * 2);
    f16*   Xc    = (f16*)carve((size_t)ROWS_CH * 256 * 2);
    f16*   Zc0   = (f16*)carve((size_t)ROWS_CH * NG * 2);
    f16*   H0c   = (f16*)carve((size_t)ROWS_CH * 512 * 2);
    f16*   Zc1   = (f16*)carve((size_t)ROWS_CH * NG * 2);

    hipMemsetAsync(ring0, 0, (size_t)4 * 8 * 2048 * 8, stream);
    hipMemsetAsync(ring1, 0, (size_t)4 * 8 * 2048 * 8, stream);

    k_packW<<<384, 256, 0, stream>>>(gw0, 768, 0,    giw0, Wx0, 256);
    k_packW<<<768, 256, 0, stream>>>(gw0, 768, 256,  ghw0, Wh0, 512);
    k_packW<<<768, 256, 0, stream>>>(gw1, 1024, 0,   giw1, Wx1, 512);
    k_packW<<<768, 256, 0, stream>>>(gw1, 1024, 512, ghw1, Wh1, 512);
    k_packBias<<<6, 256, 0, stream>>>(gb0, gib0, bias0);
    k_packBias<<<6, 256, 0, stream>>>(gb1, gib1, bias1);

    dim3 gemmGrid(NG / 64, ROWS_CH / 64);   // (24, 128)
    for (int ch = 0; ch < NCHUNK; ++ch) {
        int t0 = ch * TCH;
        k_embed<<<ROWS_CH * 64 / 256, 256, 0, stream>>>(tokens, emb, Xc, t0);
        k_gemm<<<gemmGrid, 256, 0, stream>>>(Xc, Wx0, bias0, Zc0, 256);
        // L0 of chunk ch runs concurrently with L1 of chunk ch-1
        k_recur5<<<256, 256, 0, stream>>>(Wh0, Wh1, Zc0, Zc1, ghb0, ghb1,
                                          ring0, ring1, H0c, h1out,
                                          t0, TCH, t0 - TCH, ch ? TCH : 0);
        k_gemm<<<gemmGrid, 256, 0, stream>>>(H0c, Wx1, bias1, Zc1, 512);
    }
    // drain: last chunk of layer 1
    k_recur5<<<256, 256, 0, stream>>>(Wh0, Wh1, Zc0, Zc1, ghb0, ghb1,
                                      ring0, ring1, H0c, h1out,
                                      0, 0, (NCHUNK - 1) * TCH, TCH);
    k_final<<<1, 64, 0, stream>>>(h1out, fc_w, fc_b, (float*)d_out);
}

// Round 12
// 3893.676 us; speedup vs baseline: 1.2847x; 1.2847x over previous
//
#include <hip/hip_runtime.h>

typedef _Float16 f16;
typedef _Float16 f16x8 __attribute__((ext_vector_type(8)));
typedef float f32x4 __attribute__((ext_vector_type(4)));
typedef unsigned long long u64;

#define B_ 64
#define S_ 1024
#define E_ 256
#define H_ 512
#define NG 1536
#define V_ 50257
#define HS_LD 544       // h LDS row stride (f16) — R9-proven
#define XLS_LD 272      // x LDS row stride (f16)
#define DSLOT 64        // deep h0 ring slots
#define LAG 24          // L1 starts this many steps behind L0
#define LEAD 40         // L0 anti-overrun probe depth (LAG < LEAD < DSLOT-2)

__device__ __forceinline__ float sigm(float x) { return 1.f / (1.f + __expf(-x)); }

#define ALOAD(p) __hip_atomic_load((p), __ATOMIC_RELAXED, __HIP_MEMORY_SCOPE_AGENT)
#define ASTORE(p, v) __hip_atomic_store((p), (v), __ATOMIC_RELAXED, __HIP_MEMORY_SCOPE_AGENT)

// ------------- pack [gate_w slice ; gi_or_gh_w] into fp16 [1536][KK] -------------
__global__ __launch_bounds__(256) void k_packW(const float* __restrict__ gw, int ld, int off,
        const float* __restrict__ g2, f16* __restrict__ W, int KK) {
    int idx = blockIdx.x * 256 + threadIdx.x;
    int per = KK >> 2;
    if (idx >= NG * per) return;
    int row = idx / per;
    int c4 = (idx % per) << 2;
    const float* src = (row < 1024) ? gw + (size_t)row * ld + off + c4
                                    : g2 + (size_t)(row - 1024) * KK + c4;
    float4 v = *reinterpret_cast<const float4*>(src);
    union { f16 h[4]; u64 u; } w;
    w.h[0] = (f16)v.x; w.h[1] = (f16)v.y; w.h[2] = (f16)v.z; w.h[3] = (f16)v.w;
    *reinterpret_cast<u64*>(W + (size_t)row * KK + c4) = w.u;
}

// ------------------------- emb fp32 -> fp16 (one-time) -------------------------
__global__ __launch_bounds__(256) void k_embconv(const float* __restrict__ emb,
        f16* __restrict__ out) {
    long long i = (long long)blockIdx.x * 256 + threadIdx.x;
    if (i >= (long long)V_ * E_ / 4) return;
    float4 v = reinterpret_cast<const float4*>(emb)[i];
    union { f16 h[4]; u64 u; } w;
    w.h[0] = (f16)v.x; w.h[1] = (f16)v.y; w.h[2] = (f16)v.z; w.h[3] = (f16)v.w;
    reinterpret_cast<u64*>(out)[i] = w.u;
}

// ------------- fused persistent 2-layer GRU: R9 step internals + deep lag -------------
// 256 WGs x 256 thr (1/CU). c=blk&7 (cluster of 8 batches), l=(blk>>3)&1, gg=blk>>4:
// WG owns 32 outputs of its layer. Wave = 2 MFMA tiles; A-rows per output {r,z,n_h,n_x}
// fold the h-matmul AND x-matmul into one C tile. Weights register-resident.
// Exchange: R9's tag-in-data granules (u64 = tag<<32 | 2xf16, relaxed agent atomics,
// chained per-granule retry, gathered contiguous publish, two barriers per step).
// DECOUPLING: L1 starts LAG steps late (one-time poll) and reads h0(s+1) from a
// DSLOT-deep ring written ~LAG steps earlier -> tags always fresh, zero cross-layer
// waits in steady state. L0's anti-overrun probe (LEAD) also passes instantly.
__global__ __launch_bounds__(256, 1) void k_fused(
    const f16* __restrict__ Wx0p, const f16* __restrict__ Wh0p,
    const f16* __restrict__ Wx1p, const f16* __restrict__ Wh1p,
    const float* __restrict__ gb0, const float* __restrict__ gib0, const float* __restrict__ ghb0,
    const float* __restrict__ gb1, const float* __restrict__ gib1, const float* __restrict__ ghb1,
    const int* __restrict__ tok, const f16* __restrict__ embh,
    u64* ring0, u64* ring1, u64* d0r, f16* __restrict__ h1out)
{
    __shared__ __align__(16) f16 HSa[8][HS_LD];      // h-state (h0 for L0 / h1 for L1)
    __shared__ __align__(16) f16 HSb[8][HS_LD];      // L1: h0(s+1) x-input
    __shared__ __align__(16) f16 xls[2][8][XLS_LD];  // L0: x(t) double buffer
    __shared__ __align__(16) f16 hx[8][40];          // gathered h_next (R9 layout)
    const int blk = blockIdx.x;
    const int c = blk & 7;
    const int l = (blk >> 3) & 1;
    const int gg = blk >> 4;                         // 0..15
    const int i0 = gg << 5;
    const int tid = threadIdx.x;
    const int w = tid >> 6, lane = tid & 63;
    const int colb = lane & 15, bq = lane & 7, j4 = lane >> 4;
    const int rrow = lane & 15;
    const int ol = rrow >> 2, gate = rrow & 3;       // A-row = ol*4 + gate

    const f16* Whp = l ? Wh1p : Wh0p;
    const f16* Wxp = l ? Wx1p : Wx0p;
    const int KXn = l ? 16 : 8;                      // x-side MFMA t-steps
    const int KXw = l ? 512 : 256;

    // ---- weights into registers (constant all 1024 steps) ----
    // Wh rows per output: gate 0->r, 1->z, 2->n_h, 3->zero
    // Wx rows per output: gate 0->r, 1->z, 2->zero, 3->n_x (row 1024+out)
    f16x8 wh[2][16], wx[2][16];
    #pragma unroll
    for (int tl = 0; tl < 2; ++tl) {
        const int out = i0 + (w << 3) + (tl << 2) + ol;
        const int rH = (gate < 3) ? (gate * 512 + out) : -1;
        const int rX = (gate < 2) ? (gate * 512 + out) : (gate == 3 ? 1024 + out : -1);
        #pragma unroll
        for (int t = 0; t < 16; ++t) {
            f16x8 v{};
            if (rH >= 0) v = *(const f16x8*)(Whp + (size_t)rH * 512 + (t << 5) + (j4 << 3));
            wh[tl][t] = v;
        }
        #pragma unroll
        for (int t = 0; t < 16; ++t) {
            f16x8 v{};
            if (rX >= 0 && t < KXn)
                v = *(const f16x8*)(Wxp + (size_t)rX * KXw + (t << 5) + (j4 << 3));
            wx[tl][t] = v;
        }
    }
    const float* gb  = l ? gb1 : gb0;
    const float* gib = l ? gib1 : gib0;
    const float* ghb = l ? ghb1 : ghb0;
    const int outA = i0 + (w << 3) + j4, outB = outA + 4;
    const float bRA = gb[outA], bZA = gb[512 + outA], bIA = gib[outA], bHA = ghb[outA];
    const float bRB = gb[outB], bZB = gb[512 + outB], bIB = gib[outB], bHB = ghb[outB];

    if (l == 0) {
        // prologue: stage x(0)
        if (tid < 128) {
            int sb = tid >> 4, seg = tid & 15;
            int tk = tok[((c << 3) + sb) * S_];
            const f16* ep = embh + (size_t)tk * E_ + (seg << 4);
            *(f16x8*)&xls[0][sb][seg << 4]       = *(const f16x8*)ep;
            *(f16x8*)&xls[0][sb][(seg << 4) + 8] = *(const f16x8*)(ep + 8);
        }
        __syncthreads();
        for (int s = 0; s < S_; ++s) {
            const int cur = s & 1;
            // x(s+1) prefetch into regs (independent; overlaps stage wait)
            f16x8 e0{}, e1{};
            const bool havex = (tid < 128) && (s + 1 < S_);
            if (havex) {
                int tk = tok[((c << 3) + (tid >> 4)) * S_ + s + 1];
                const f16* ep = embh + (size_t)tk * E_ + ((tid & 15) << 4);
                e0 = *(const f16x8*)ep; e1 = *(const f16x8*)(ep + 8);
            }
            // stage h0(s): issue 8 loads, probe, then chained retry (R9 internals)
            {
                const u64* src = ring0 + ((size_t)(s & 3) * 8 + c) * 2048;
                u64 g[8];
                #pragma unroll
                for (int i = 0; i < 8; ++i) g[i] = ALOAD(src + (i << 8) + tid);
                // anti-overrun probe: L1 published tag >= s-LEAD (instant: L1 lags ~LAG<LEAD)
                if (tid == 0 && s >= LEAD) {
                    const u64* pr = ring1 + ((size_t)((s - LEAD) & 3) * 8 + c) * 2048;
                    while ((unsigned)(ALOAD(pr) >> 32) < (unsigned)(s - LEAD)) {}
                }
                #pragma unroll
                for (int i = 0; i < 8; ++i) {
                    while ((unsigned)(g[i] >> 32) != (unsigned)s)
                        g[i] = ALOAD(src + (i << 8) + tid);
                    *reinterpret_cast<unsigned*>(
                        &HSa[i][((tid >> 4) << 5) + ((tid & 15) << 1)]) = (unsigned)g[i];
                }
            }
            __syncthreads();
            // MFMA: Wh0 @ h0(s) (16 t) + Wx0 @ x(s) (8 t), 2 tiles, shared B
            f32x4 p00{}, p01{}, p10{}, p11{};
            #pragma unroll
            for (int t = 0; t < 16; ++t) {
                f16x8 bf = *(const f16x8*)&HSa[bq][(t << 5) + (j4 << 3)];
                if (t & 1) { p01 = __builtin_amdgcn_mfma_f32_16x16x32_f16(wh[0][t], bf, p01, 0, 0, 0);
                             p11 = __builtin_amdgcn_mfma_f32_16x16x32_f16(wh[1][t], bf, p11, 0, 0, 0); }
                else       { p00 = __builtin_amdgcn_mfma_f32_16x16x32_f16(wh[0][t], bf, p00, 0, 0, 0);
                             p10 = __builtin_amdgcn_mfma_f32_16x16x32_f16(wh[1][t], bf, p10, 0, 0, 0); }
            }
            #pragma unroll
            for (int t = 0; t < 8; ++t) {
                f16x8 bf = *(const f16x8*)&xls[cur][bq][(t << 5) + (j4 << 3)];
                if (t & 1) { p01 = __builtin_amdgcn_mfma_f32_16x16x32_f16(wx[0][t], bf, p01, 0, 0, 0);
                             p11 = __builtin_amdgcn_mfma_f32_16x16x32_f16(wx[1][t], bf, p11, 0, 0, 0); }
                else       { p00 = __builtin_amdgcn_mfma_f32_16x16x32_f16(wx[0][t], bf, p00, 0, 0, 0);
                             p10 = __builtin_amdgcn_mfma_f32_16x16x32_f16(wx[1][t], bf, p10, 0, 0, 0); }
            }
            f32x4 dA = p00 + p01, dB = p10 + p11;    // rows {r, z, n_h, n_x}
            if (colb < 8) {
                float rA = sigm(dA[0] + bRA), zA = sigm(dA[1] + bZA);
                float nA = tanhf(dA[3] + bIA + rA * (dA[2] + bHA));
                float hA = (float)HSa[bq][outA];
                float rB = sigm(dB[0] + bRB), zB = sigm(dB[1] + bZB);
                float nB = tanhf(dB[3] + bIB + rB * (dB[2] + bHB));
                float hB = (float)HSa[bq][outB];
                hx[bq][(w << 3) + j4]     = (f16)((1.f - zA) * nA + zA * hA);
                hx[bq][(w << 3) + 4 + j4] = (f16)((1.f - zB) * nB + zB * hB);
            }
            if (havex) {
                int sb = tid >> 4, seg = tid & 15;
                *(f16x8*)&xls[cur ^ 1][sb][seg << 4]       = e0;
                *(f16x8*)&xls[cur ^ 1][sb][(seg << 4) + 8] = e1;
            }
            __syncthreads();
            // gathered publish (R9 internals): own 4-ring + deep ring
            if (tid < 128) {
                const int b = tid >> 4, d = tid & 15;
                unsigned dval = *reinterpret_cast<const unsigned*>(&hx[b][d << 1]);
                u64 gr = ((u64)(unsigned)(s + 1) << 32) | (u64)dval;
                const size_t gi = ((size_t)b << 8) + (gg << 4) + d;
                ASTORE(ring0 + ((size_t)((s + 1) & 3) * 8 + c) * 2048 + gi, gr);
                ASTORE(d0r + ((size_t)((s + 1) & (DSLOT - 1)) * 8 + c) * 2048 + gi, gr);
            }
        }
    } else {
        // one-time start lag: wait until L0 has reached step LAG
        if (tid == 0) {
            const u64* pp = d0r + ((size_t)(LAG & (DSLOT - 1)) * 8 + c) * 2048;
            while ((unsigned)(ALOAD(pp) >> 32) < (unsigned)LAG) {}
        }
        __syncthreads();
        for (int s = 0; s < S_; ++s) {
            // stage h1(s) [own ring] + h0(s+1) [deep ring, ~LAG steps old -> fresh]
            {
                const u64* s1 = ring1 + ((size_t)(s & 3) * 8 + c) * 2048;
                const u64* s0 = d0r + ((size_t)((s + 1) & (DSLOT - 1)) * 8 + c) * 2048;
                u64 g1[8], g0[8];
                #pragma unroll
                for (int i = 0; i < 8; ++i) g1[i] = ALOAD(s1 + (i << 8) + tid);
                #pragma unroll
                for (int i = 0; i < 8; ++i) g0[i] = ALOAD(s0 + (i << 8) + tid);
                #pragma unroll
                for (int i = 0; i < 8; ++i) {
                    while ((unsigned)(g1[i] >> 32) != (unsigned)s)
                        g1[i] = ALOAD(s1 + (i << 8) + tid);
                    *reinterpret_cast<unsigned*>(
                        &HSa[i][((tid >> 4) << 5) + ((tid & 15) << 1)]) = (unsigned)g1[i];
                }
                #pragma unroll
                for (int i = 0; i < 8; ++i) {
                    while ((unsigned)(g0[i] >> 32) != (unsigned)(s + 1))
                        g0[i] = ALOAD(s0 + (i << 8) + tid);
                    *reinterpret_cast<unsigned*>(
                        &HSb[i][((tid >> 4) << 5) + ((tid & 15) << 1)]) = (unsigned)g0[i];
                }
            }
            __syncthreads();
            // MFMA: Wh1 @ h1(s) + Wx1 @ h0(s+1), both K=512, 2 tiles, shared B
            f32x4 p00{}, p01{}, p10{}, p11{};
            #pragma unroll
            for (int t = 0; t < 16; ++t) {
                f16x8 bf = *(const f16x8*)&HSa[bq][(t << 5) + (j4 << 3)];
                if (t & 1) { p01 = __builtin_amdgcn_mfma_f32_16x16x32_f16(wh[0][t], bf, p01, 0, 0, 0);
                             p11 = __builtin_amdgcn_mfma_f32_16x16x32_f16(wh[1][t], bf, p11, 0, 0, 0); }
                else       { p00 = __builtin_amdgcn_mfma_f32_16x16x32_f16(wh[0][t], bf, p00, 0, 0, 0);
                             p10 = __builtin_amdgcn_mfma_f32_16x16x32_f16(wh[1][t], bf, p10, 0, 0, 0); }
            }
            #pragma unroll
            for (int t = 0; t < 16; ++t) {
                f16x8 bf = *(const f16x8*)&HSb[bq][(t << 5) + (j4 << 3)];
                if (t & 1) { p01 = __builtin_amdgcn_mfma_f32_16x16x32_f16(wx[0][t], bf, p01, 0, 0, 0);
                             p11 = __builtin_amdgcn_mfma_f32_16x16x32_f16(wx[1][t], bf, p11, 0, 0, 0); }
                else       { p00 = __builtin_amdgcn_mfma_f32_16x16x32_f16(wx[0][t], bf, p00, 0, 0, 0);
                             p10 = __builtin_amdgcn_mfma_f32_16x16x32_f16(wx[1][t], bf, p10, 0, 0, 0); }
            }
            f32x4 dA = p00 + p01, dB = p10 + p11;    // rows {r, z, n_h, n_x}
            if (colb < 8) {
                float rA = sigm(dA[0] + bRA), zA = sigm(dA[1] + bZA);
                float nA = tanhf(dA[3] + bIA + rA * (dA[2] + bHA));
                float hA = (float)HSa[bq][outA];
                float rB = sigm(dB[0] + bRB), zB = sigm(dB[1] + bZB);
                float nB = tanhf(dB[3] + bIB + rB * (dB[2] + bHB));
                float hB = (float)HSa[bq][outB];
                hx[bq][(w << 3) + j4]     = (f16)((1.f - zA) * nA + zA * hA);
                hx[bq][(w << 3) + 4 + j4] = (f16)((1.f - zB) * nB + zB * hB);
            }
            __syncthreads();
            // gathered publish; final step also writes plain h1out for the head
            if (tid < 128) {
                const int b = tid >> 4, d = tid & 15;
                unsigned dval = *reinterpret_cast<const unsigned*>(&hx[b][d << 1]);
                u64 gr = ((u64)(unsigned)(s + 1) << 32) | (u64)dval;
                ASTORE(ring1 + ((size_t)((s + 1) & 3) * 8 + c) * 2048
                             + ((size_t)b << 8) + (gg << 4) + d, gr);
                if (s == S_ - 1)
                    *reinterpret_cast<unsigned*>(
                        &h1out[((size_t)(c << 3) + b) * H_ + i0 + (d << 1)]) = dval;
            }
        }
    }
}

// ------------------------------- final head -------------------------------
__global__ __launch_bounds__(64) void k_final(const f16* __restrict__ h,
        const float* __restrict__ fcw, const float* __restrict__ fcb,
        float* __restrict__ out) {
    int b = threadIdx.x;
    float acc = fcb[0];
    for (int k = 0; k < H_; ++k) acc += (float)h[(size_t)b * H_ + k] * fcw[k];
    out[b] = sigm(acc);
}

extern "C" void kernel_launch(void* const* d_in, const int* in_sizes, int n_in,
                              void* d_out, int out_size, void* d_ws, size_t ws_size,
                              hipStream_t stream) {
    (void)in_sizes; (void)n_in; (void)out_size; (void)ws_size;
    const int*   tokens = (const int*)d_in[0];
    const float* emb  = (const float*)d_in[1];
    const float* fc_w = (const float*)d_in[2];
    const float* fc_b = (const float*)d_in[3];
    const float* gw0  = (const float*)d_in[4];
    const float* gb0  = (const float*)d_in[5];
    const float* giw0 = (const float*)d_in[6];
    const float* gib0 = (const float*)d_in[7];
    const float* ghw0 = (const float*)d_in[8];
    const float* ghb0 = (const float*)d_in[9];
    const float* gw1  = (const float*)d_in[10];
    const float* gb1  = (const float*)d_in[11];
    const float* giw1 = (const float*)d_in[12];
    const float* gib1 = (const float*)d_in[13];
    const float* ghw1 = (const float*)d_in[14];
    const float* ghb1 = (const float*)d_in[15];

    char* base = (char*)d_ws;
    size_t off = 0;
    auto carve = [&](size_t bytes) {
        char* p = base + off;
        off = (off + bytes + 255) & ~(size_t)255;
        return p;
    };
    f16*   embh  = (f16*)carve((size_t)V_ * E_ * 2);              // ~25.7 MB
    f16*   Wx0   = (f16*)carve((size_t)NG * 256 * 2);
    f16*   Wh0   = (f16*)carve((size_t)NG * 512 * 2);
    f16*   Wx1   = (f16*)carve((size_t)NG * 512 * 2);
    f16*   Wh1   = (f16*)carve((size_t)NG * 512 * 2);
    u64*   ring0 = (u64*)carve((size_t)4 * 8 * 2048 * 8);         // 512 KB
    u64*   ring1 = (u64*)carve((size_t)4 * 8 * 2048 * 8);         // 512 KB
    u64*   d0r   = (u64*)carve((size_t)DSLOT * 8 * 2048 * 8);     // 8 MB deep h0 ring
    f16*   h1out = (f16*)carve((size_t)B_ * H_ * 2);

    hipMemsetAsync(ring0, 0, (size_t)4 * 8 * 2048 * 8, stream);
    hipMemsetAsync(ring1, 0, (size_t)4 * 8 * 2048 * 8, stream);
    hipMemsetAsync(d0r, 0, (size_t)DSLOT * 8 * 2048 * 8, stream);

    k_embconv<<<(V_ * E_ / 4 + 255) / 256, 256, 0, stream>>>(emb, embh);
    k_packW<<<384, 256, 0, stream>>>(gw0, 768, 0,    giw0, Wx0, 256);
    k_packW<<<768, 256, 0, stream>>>(gw0, 768, 256,  ghw0, Wh0, 512);
    k_packW<<<768, 256, 0, stream>>>(gw1, 1024, 0,   giw1, Wx1, 512);
    k_packW<<<768, 256, 0, stream>>>(gw1, 1024, 512, ghw1, Wh1, 512);

    k_fused<<<256, 256, 0, stream>>>(Wx0, Wh0, Wx1, Wh1,
                                     gb0, gib0, ghb0, gb1, gib1, ghb1,
                                     tokens, embh, ring0, ring1, d0r, h1out);
    k_final<<<1, 64, 0, stream>>>(h1out, fc_w, fc_b, (float*)d_out);
}

// Round 14
// 3568.025 us; speedup vs baseline: 1.4020x; 1.0913x over previous
//
#include <hip/hip_runtime.h>

typedef _Float16 f16;
typedef _Float16 f16x8 __attribute__((ext_vector_type(8)));
typedef float f32x4 __attribute__((ext_vector_type(4)));
typedef unsigned long long u64;

#define B_ 64
#define S_ 1024
#define E_ 256
#define H_ 512
#define NG 1536
#define V_ 50257
#define HS_LD 544       // recur h LDS row stride (R9-proven)
#define ZSLOT 32        // Z ring slots
#define DSLOT 64        // deep h0 ring slots

__device__ __forceinline__ float sigm(float x) { return 1.f / (1.f + __expf(-x)); }

#define ALOAD(p) __hip_atomic_load((p), __ATOMIC_RELAXED, __HIP_MEMORY_SCOPE_AGENT)
#define ASTORE(p, v) __hip_atomic_store((p), (v), __ATOMIC_RELAXED, __HIP_MEMORY_SCOPE_AGENT)
#define AADD(p, v) __hip_atomic_fetch_add((p), (v), __ATOMIC_RELAXED, __HIP_MEMORY_SCOPE_AGENT)

__device__ __forceinline__ float zxt(u64 g, int odd) {
    unsigned short u = (unsigned short)(odd ? (g >> 16) : g);
    return (float)__builtin_bit_cast(f16, u);
}
__device__ __forceinline__ u64 pk2(float a, float b) {
    unsigned short ua = __builtin_bit_cast(unsigned short, (f16)a);
    unsigned short ub = __builtin_bit_cast(unsigned short, (f16)b);
    return (u64)ua | ((u64)ub << 16);
}

// ------------- pack [gate_w slice ; gi_or_gh_w] into fp16 [1536][KK] -------------
__global__ __launch_bounds__(256) void k_packW(const float* __restrict__ gw, int ld, int off,
        const float* __restrict__ g2, f16* __restrict__ W, int KK) {
    int idx = blockIdx.x * 256 + threadIdx.x;
    int per = KK >> 2;
    if (idx >= NG * per) return;
    int row = idx / per;
    int c4 = (idx % per) << 2;
    const float* src = (row < 1024) ? gw + (size_t)row * ld + off + c4
                                    : g2 + (size_t)(row - 1024) * KK + c4;
    float4 v = *reinterpret_cast<const float4*>(src);
    union { f16 h[4]; u64 u; } w;
    w.h[0] = (f16)v.x; w.h[1] = (f16)v.y; w.h[2] = (f16)v.z; w.h[3] = (f16)v.w;
    *reinterpret_cast<u64*>(W + (size_t)row * KK + c4) = w.u;
}

__global__ __launch_bounds__(256) void k_packBias(const float* __restrict__ gb,
        const float* __restrict__ gib, float* __restrict__ bias) {
    int i = blockIdx.x * 256 + threadIdx.x;
    if (i < 1024) bias[i] = gb[i];
    else if (i < NG) bias[i] = gib[i - 1024];
}

__global__ __launch_bounds__(256) void k_embconv(const float* __restrict__ emb,
        f16* __restrict__ out) {
    long long i = (long long)blockIdx.x * 256 + threadIdx.x;
    if (i >= (long long)V_ * E_ / 4) return;
    float4 v = reinterpret_cast<const float4*>(emb)[i];
    union { f16 h[4]; u64 u; } w;
    w.h[0] = (f16)v.x; w.h[1] = (f16)v.y; w.h[2] = (f16)v.z; w.h[3] = (f16)v.w;
    reinterpret_cast<u64*>(out)[i] = w.u;
}

// =================== mega persistent kernel: 400 WGs, 4 roles ===================
// blk <128: L0 recur (c=blk&7, gg=blk>>3) — R9 step verbatim, Z from z0 ring (tagged)
// blk <256: L1 recur                      — R9 step verbatim, Z from z1 ring (tagged)
// blk <352: Z1 workers (96 = 24 col-tiles x 4 phases): Z1[t] = Wx1 @ h0(t+1) + bias1
// else    : Z0 workers (48 = 24 col-tiles x 2 phases): Z0[t] = Wx0 @ x(t) + bias0
// Exchange media: tag-in-data u64 granules, relaxed agent atomics (R9-proven).
// h rings: tag s+1 | 2xf16.  Z rings: tag t+1 | 2xf16 (cols 2k,2k+1).
// Pacing: Z workers probe consumer ring tags (>= t-28); L0 probes zflag1[s-60]==24
// before deep-slot reuse.  Dep chain strictly decreasing in step -> deadlock-free.
// FIX vs R13: Z1 h0 staging now covers ALL 16384 granules/slot (was 8192 -> half
// the batches unstaged -> absmax 0.11).  Decode: bt = idx>>8, col = (idx&255)*2.
__global__ __launch_bounds__(256, 2) void k_mega(
    const f16* __restrict__ Wx0, const f16* __restrict__ Wh0,
    const f16* __restrict__ Wx1, const f16* __restrict__ Wh1,
    const float* __restrict__ bias0c, const float* __restrict__ bias1c,
    const float* __restrict__ ghb0, const float* __restrict__ ghb1,
    const int* __restrict__ tok, const f16* __restrict__ embh,
    u64* ring0, u64* ring1, u64* d0r, u64* z0r, u64* z1r,
    int* zflag1, f16* __restrict__ h1out)
{
    __shared__ __align__(16) unsigned char LDS_[65536];
    const int blk = blockIdx.x;
    const int tid = threadIdx.x;

    if (blk < 256) {
        // ======================= recur role (R9 step internals) =======================
        const int l = blk >> 7;
        const int q = blk & 127;
        const int c = q & 7, gg = q >> 3;
        const int i0 = gg << 5;
        const int w = tid >> 6, lane = tid & 63;
        const int colb = lane & 15, bq = lane & 7, j4 = lane >> 4;
        const int rrow = lane & 15;
        const int ol = rrow >> 2, gate = rrow & 3;
        const f16* Wh = l ? Wh1 : Wh0;
        const float* ghb = l ? ghb1 : ghb0;
        u64* ring = l ? ring1 : ring0;
        const u64* zr = l ? z1r : z0r;
        f16* HS = (f16*)LDS_;                       // [8][HS_LD]
        f16* hx = (f16*)(LDS_ + 8 * HS_LD * 2);     // [8][40]

        f16x8 wA[2][16];
        #pragma unroll
        for (int tl = 0; tl < 2; ++tl) {
            const int out = i0 + (w << 3) + (tl << 2) + ol;
            #pragma unroll
            for (int t = 0; t < 16; ++t) {
                f16x8 v{};
                if (gate < 3)
                    v = *reinterpret_cast<const f16x8*>(
                            Wh + ((size_t)(gate * H_ + out)) * H_ + (t << 5) + (j4 << 3));
                wA[tl][t] = v;
            }
        }
        const int outA = i0 + (w << 3) + j4, outB = outA + 4;
        const float gbA = ghb[outA], gbB = ghb[outB];
        const int batch = (c << 3) + bq;
        const int par = j4 & 1;                     // parity of outA and outB
        const size_t zoA = (size_t)(outA >> 1), zoB = (size_t)(outB >> 1);

        for (int s = 0; s < S_; ++s) {
            // ---- Z reads: 6 tagged granules (issue early; finish after h stage) ----
            const u64* zs = zr + (size_t)(s & (ZSLOT - 1)) * 49152 + (size_t)batch * 768;
            u64 zg0 = ALOAD(zs + zoA),        zg1 = ALOAD(zs + zoB);
            u64 zg2 = ALOAD(zs + 256 + zoA),  zg3 = ALOAD(zs + 256 + zoB);
            u64 zg4 = ALOAD(zs + 512 + zoA),  zg5 = ALOAD(zs + 512 + zoB);
            // ---- L0: deep-ring overwrite safety probe (steady state: instant) ----
            if (!l && s >= 64) {
                const int* zf = zflag1 + (s - 60);
                while (ALOAD(zf) < 24) {}
            }
            // ---- stage h(s): 8 tagged granules/thread, chained retry (R9 exact) ----
            {
                const u64* src = ring + ((size_t)(s & 3) * 8 + c) * 2048;
                u64 g[8];
                #pragma unroll
                for (int i = 0; i < 8; ++i) g[i] = ALOAD(src + (i << 8) + tid);
                #pragma unroll
                for (int i = 0; i < 8; ++i) {
                    while ((unsigned)(g[i] >> 32) != (unsigned)s)
                        g[i] = ALOAD(src + (i << 8) + tid);
                    *reinterpret_cast<unsigned*>(
                        &HS[i * HS_LD + ((tid >> 4) << 5) + ((tid & 15) << 1)]) = (unsigned)g[i];
                }
            }
            // ---- finish Z retries (usually fresh) ----
            const unsigned ztg = (unsigned)(s + 1);
            while ((unsigned)(zg0 >> 32) != ztg) zg0 = ALOAD(zs + zoA);
            while ((unsigned)(zg1 >> 32) != ztg) zg1 = ALOAD(zs + zoB);
            while ((unsigned)(zg2 >> 32) != ztg) zg2 = ALOAD(zs + 256 + zoA);
            while ((unsigned)(zg3 >> 32) != ztg) zg3 = ALOAD(zs + 256 + zoB);
            while ((unsigned)(zg4 >> 32) != ztg) zg4 = ALOAD(zs + 512 + zoA);
            while ((unsigned)(zg5 >> 32) != ztg) zg5 = ALOAD(zs + 512 + zoB);
            __syncthreads();
            // ---- MFMA: 2 tiles x K=512 (R9 exact) ----
            f32x4 a00{}, a01{}, a10{}, a11{};
            #pragma unroll
            for (int t = 0; t < 16; ++t) {
                f16x8 bf = *reinterpret_cast<const f16x8*>(&HS[bq * HS_LD + (t << 5) + (j4 << 3)]);
                if (t & 1) {
                    a01 = __builtin_amdgcn_mfma_f32_16x16x32_f16(wA[0][t], bf, a01, 0, 0, 0);
                    a11 = __builtin_amdgcn_mfma_f32_16x16x32_f16(wA[1][t], bf, a11, 0, 0, 0);
                } else {
                    a00 = __builtin_amdgcn_mfma_f32_16x16x32_f16(wA[0][t], bf, a00, 0, 0, 0);
                    a10 = __builtin_amdgcn_mfma_f32_16x16x32_f16(wA[1][t], bf, a10, 0, 0, 0);
                }
            }
            f32x4 dA = a00 + a01, dB = a10 + a11;   // rows {r, z, n_h, pad}
            if (colb < 8) {
                float holdA = (float)HS[bq * HS_LD + outA];
                float holdB = (float)HS[bq * HS_LD + outB];
                float rA = sigm(zxt(zg0, par) + dA[0]);
                float zA = sigm(zxt(zg2, par) + dA[1]);
                float nA = tanhf(zxt(zg4, par) + rA * (dA[2] + gbA));
                float rB = sigm(zxt(zg1, par) + dB[0]);
                float zB = sigm(zxt(zg3, par) + dB[1]);
                float nB = tanhf(zxt(zg5, par) + rB * (dB[2] + gbB));
                hx[bq * 40 + (w << 3) + j4]     = (f16)((1.f - zA) * nA + zA * holdA);
                hx[bq * 40 + (w << 3) + 4 + j4] = (f16)((1.f - zB) * nB + zB * holdB);
            }
            __syncthreads();
            // ---- gathered publish (R9 exact) ----
            if (tid < 128) {
                const int b = tid >> 4, d = tid & 15;
                unsigned dval = *reinterpret_cast<const unsigned*>(&hx[b * 40 + (d << 1)]);
                u64 gr = ((u64)(unsigned)(s + 1) << 32) | (u64)dval;
                const size_t gi = ((size_t)b << 8) + (gg << 4) + d;
                ASTORE(ring + ((size_t)((s + 1) & 3) * 8 + c) * 2048 + gi, gr);
                if (!l)
                    ASTORE(d0r + ((size_t)((s + 1) & (DSLOT - 1)) * 8 + c) * 2048 + gi, gr);
                else if (s == S_ - 1)
                    *reinterpret_cast<unsigned*>(
                        &h1out[((size_t)(c << 3) + b) * H_ + i0 + (d << 1)]) = dval;
            }
            __syncthreads();
        }
    } else if (blk < 352) {
        // ======================= Z1 workers: Z1[t] = Wx1 @ h0(t+1) + bias1 =======================
        const int qq = blk - 256, p = qq & 3, nt = qq >> 2;
        const int n0 = nt << 6;
        const int w = tid >> 6, lane = tid & 63;
        const int q4 = lane >> 4, l15 = lane & 15;
        f16* hst = (f16*)LDS_;                      // [64][512], XOR-swizzled
        f16x8 wxa[16];
        const int arow = n0 + (w << 4) + l15;
        #pragma unroll
        for (int t = 0; t < 16; ++t)
            wxa[t] = *reinterpret_cast<const f16x8*>(Wx1 + (size_t)arow * 512 + (t << 5) + (q4 << 3));
        const int cb = n0 + (w << 4) + (q4 << 2);
        const float bv0 = bias1c[cb], bv1 = bias1c[cb + 1], bv2 = bias1c[cb + 2], bv3 = bias1c[cb + 3];
        const int sx = (l15 & 7) << 3;

        for (int t = p; t < S_; t += 4) {
            // pacing: L1 must have passed step t-28 before Z1-slot reuse
            if (t >= 32) {
                const u64* pr = ring1 + ((size_t)((t - 28) & 3) * 8 + (lane & 7)) * 2048;
                while (!__all((int)(unsigned)(ALOAD(pr) >> 32) >= t - 28)) {}
            }
            // stage h0(t+1) from deep ring (tag t+1): ALL 16384 granules, 4 chunks x 16/thread
            {
                const u64* src = d0r + (size_t)((t + 1) & (DSLOT - 1)) * 16384;
                const unsigned tg = (unsigned)(t + 1);
                #pragma unroll
                for (int hf = 0; hf < 4; ++hf) {
                    u64 g[16]; unsigned miss = 0;
                    #pragma unroll
                    for (int j = 0; j < 16; ++j) g[j] = ALOAD(src + (hf << 12) + (j << 8) + tid);
                    #pragma unroll
                    for (int j = 0; j < 16; ++j) {
                        int idx = (hf << 12) + (j << 8) + tid;
                        int bt = idx >> 8, col = (idx & 255) << 1;
                        if ((unsigned)(g[j] >> 32) == tg)
                            *reinterpret_cast<unsigned*>(&hst[bt * 512 + (col ^ ((bt & 7) << 3))]) = (unsigned)g[j];
                        else miss |= 1u << j;
                    }
                    while (miss) {
                        #pragma unroll
                        for (int j = 0; j < 16; ++j) if (miss & (1u << j)) {
                            u64 v = ALOAD(src + (hf << 12) + (j << 8) + tid);
                            if ((unsigned)(v >> 32) == tg) {
                                int idx = (hf << 12) + (j << 8) + tid;
                                int bt = idx >> 8, col = (idx & 255) << 1;
                                *reinterpret_cast<unsigned*>(&hst[bt * 512 + (col ^ ((bt & 7) << 3))]) = (unsigned)v;
                                miss &= ~(1u << j);
                            }
                        }
                    }
                }
            }
            __syncthreads();
            if (tid == 0) AADD(zflag1 + t, 1);      // deep-slot reads done -> L0 may reuse
            // MFMA: 4 batch-group tiles x 16 k-steps
            f32x4 ac0{}, ac1{}, ac2{}, ac3{};
            #pragma unroll
            for (int t16 = 0; t16 < 16; ++t16) {
                const int ko = ((t16 << 5) + (q4 << 3)) ^ sx;
                f16x8 b0 = *reinterpret_cast<const f16x8*>(&hst[(l15)      * 512 + ko]);
                f16x8 b1 = *reinterpret_cast<const f16x8*>(&hst[(16 + l15) * 512 + ko]);
                f16x8 b2 = *reinterpret_cast<const f16x8*>(&hst[(32 + l15) * 512 + ko]);
                f16x8 b3 = *reinterpret_cast<const f16x8*>(&hst[(48 + l15) * 512 + ko]);
                ac0 = __builtin_amdgcn_mfma_f32_16x16x32_f16(wxa[t16], b0, ac0, 0, 0, 0);
                ac1 = __builtin_amdgcn_mfma_f32_16x16x32_f16(wxa[t16], b1, ac1, 0, 0, 0);
                ac2 = __builtin_amdgcn_mfma_f32_16x16x32_f16(wxa[t16], b2, ac2, 0, 0, 0);
                ac3 = __builtin_amdgcn_mfma_f32_16x16x32_f16(wxa[t16], b3, ac3, 0, 0, 0);
            }
            // store tagged Z granules
            {
                const u64 t64 = (u64)(unsigned)(t + 1) << 32;
                u64* zb = z1r + (size_t)(t & (ZSLOT - 1)) * 49152 + (cb >> 1);
                u64* b0 = zb + (size_t)(l15) * 768;
                ASTORE(b0,     t64 | pk2(ac0[0] + bv0, ac0[1] + bv1));
                ASTORE(b0 + 1, t64 | pk2(ac0[2] + bv2, ac0[3] + bv3));
                u64* b1 = zb + (size_t)(16 + l15) * 768;
                ASTORE(b1,     t64 | pk2(ac1[0] + bv0, ac1[1] + bv1));
                ASTORE(b1 + 1, t64 | pk2(ac1[2] + bv2, ac1[3] + bv3));
                u64* b2 = zb + (size_t)(32 + l15) * 768;
                ASTORE(b2,     t64 | pk2(ac2[0] + bv0, ac2[1] + bv1));
                ASTORE(b2 + 1, t64 | pk2(ac2[2] + bv2, ac2[3] + bv3));
                u64* b3 = zb + (size_t)(48 + l15) * 768;
                ASTORE(b3,     t64 | pk2(ac3[0] + bv0, ac3[1] + bv1));
                ASTORE(b3 + 1, t64 | pk2(ac3[2] + bv2, ac3[3] + bv3));
            }
            __syncthreads();                        // guard hst reuse
        }
    } else {
        // ======================= Z0 workers: Z0[t] = Wx0 @ x(t) + bias0 =======================
        const int qq = blk - 352, p = qq & 1, nt = qq >> 1;
        const int n0 = nt << 6;
        const int w = tid >> 6, lane = tid & 63;
        const int q4 = lane >> 4, l15 = lane & 15;
        f16* xst = (f16*)LDS_;                      // [64][256], XOR-swizzled
        f16x8 wxa[8];
        const int arow = n0 + (w << 4) + l15;
        #pragma unroll
        for (int t = 0; t < 8; ++t)
            wxa[t] = *reinterpret_cast<const f16x8*>(Wx0 + (size_t)arow * 256 + (t << 5) + (q4 << 3));
        const int cb = n0 + (w << 4) + (q4 << 2);
        const float bv0 = bias0c[cb], bv1 = bias0c[cb + 1], bv2 = bias0c[cb + 2], bv3 = bias0c[cb + 3];
        const int sx = (l15 & 7) << 3;
        const int sb = tid >> 2, seg = tid & 3;     // stage decode: batch, col-quarter
        const int ssx = (sb & 7) << 3;

        for (int t = p; t < S_; t += 2) {
            // pacing: L0 must have passed step t-28 before Z0-slot reuse
            if (t >= 32) {
                const u64* pr = ring0 + ((size_t)((t - 28) & 3) * 8 + (lane & 7)) * 2048;
                while (!__all((int)(unsigned)(ALOAD(pr) >> 32) >= t - 28)) {}
            }
            // stage x(t): gather from embh (no tags needed)
            {
                int tk = tok[sb * S_ + t];
                const f16* ep = embh + (size_t)tk * E_ + (seg << 6);
                #pragma unroll
                for (int j = 0; j < 8; ++j)
                    *reinterpret_cast<f16x8*>(&xst[sb * 256 + ((((seg << 6) + (j << 3))) ^ ssx)]) =
                        *reinterpret_cast<const f16x8*>(ep + (j << 3));
            }
            __syncthreads();
            f32x4 ac0{}, ac1{}, ac2{}, ac3{};
            #pragma unroll
            for (int t8 = 0; t8 < 8; ++t8) {
                const int ko = ((t8 << 5) + (q4 << 3)) ^ sx;
                f16x8 b0 = *reinterpret_cast<const f16x8*>(&xst[(l15)      * 256 + ko]);
                f16x8 b1 = *reinterpret_cast<const f16x8*>(&xst[(16 + l15) * 256 + ko]);
                f16x8 b2 = *reinterpret_cast<const f16x8*>(&xst[(32 + l15) * 256 + ko]);
                f16x8 b3 = *reinterpret_cast<const f16x8*>(&xst[(48 + l15) * 256 + ko]);
                ac0 = __builtin_amdgcn_mfma_f32_16x16x32_f16(wxa[t8], b0, ac0, 0, 0, 0);
                ac1 = __builtin_amdgcn_mfma_f32_16x16x32_f16(wxa[t8], b1, ac1, 0, 0, 0);
                ac2 = __builtin_amdgcn_mfma_f32_16x16x32_f16(wxa[t8], b2, ac2, 0, 0, 0);
                ac3 = __builtin_amdgcn_mfma_f32_16x16x32_f16(wxa[t8], b3, ac3, 0, 0, 0);
            }
            {
                const u64 t64 = (u64)(unsigned)(t + 1) << 32;
                u64* zb = z0r + (size_t)(t & (ZSLOT - 1)) * 49152 + (cb >> 1);
                u64* b0 = zb + (size_t)(l15) * 768;
                ASTORE(b0,     t64 | pk2(ac0[0] + bv0, ac0[1] + bv1));
                ASTORE(b0 + 1, t64 | pk2(ac0[2] + bv2, ac0[3] + bv3));
                u64* b1 = zb + (size_t)(16 + l15) * 768;
                ASTORE(b1,     t64 | pk2(ac1[0] + bv0, ac1[1] + bv1));
                ASTORE(b1 + 1, t64 | pk2(ac1[2] + bv2, ac1[3] + bv3));
                u64* b2 = zb + (size_t)(32 + l15) * 768;
                ASTORE(b2,     t64 | pk2(ac2[0] + bv0, ac2[1] + bv1));
                ASTORE(b2 + 1, t64 | pk2(ac2[2] + bv2, ac2[3] + bv3));
                u64* b3 = zb + (size_t)(48 + l15) * 768;
                ASTORE(b3,     t64 | pk2(ac3[0] + bv0, ac3[1] + bv1));
                ASTORE(b3 + 1, t64 | pk2(ac3[2] + bv2, ac3[3] + bv3));
            }
            __syncthreads();
        }
    }
}

// ------------------------------- final head -------------------------------
__global__ __launch_bounds__(64) void k_final(const f16* __restrict__ h,
        const float* __restrict__ fcw, const float* __restrict__ fcb,
        float* __restrict__ out) {
    int b = threadIdx.x;
    float acc = fcb[0];
    for (int k = 0; k < H_; ++k) acc += (float)h[(size_t)b * H_ + k] * fcw[k];
    out[b] = sigm(acc);
}

extern "C" void kernel_launch(void* const* d_in, const int* in_sizes, int n_in,
                              void* d_out, int out_size, void* d_ws, size_t ws_size,
                              hipStream_t stream) {
    (void)in_sizes; (void)n_in; (void)out_size; (void)ws_size;
    const int*   tokens = (const int*)d_in[0];
    const float* emb  = (const float*)d_in[1];
    const float* fc_w = (const float*)d_in[2];
    const float* fc_b = (const float*)d_in[3];
    const float* gw0  = (const float*)d_in[4];
    const float* gb0  = (const float*)d_in[5];
    const float* giw0 = (const float*)d_in[6];
    const float* gib0 = (const float*)d_in[7];
    const float* ghw0 = (const float*)d_in[8];
    const float* ghb0 = (const float*)d_in[9];
    const float* gw1  = (const float*)d_in[10];
    const float* gb1  = (const float*)d_in[11];
    const float* giw1 = (const float*)d_in[12];
    const float* gib1 = (const float*)d_in[13];
    const float* ghw1 = (const float*)d_in[14];
    const float* ghb1 = (const float*)d_in[15];

    char* base = (char*)d_ws;
    size_t off = 0;
    auto carve = [&](size_t bytes) {
        char* p = base + off;
        off = (off + bytes + 255) & ~(size_t)255;
        return p;
    };
    f16*   embh   = (f16*)carve((size_t)V_ * E_ * 2);             // ~25.7 MB
    f16*   Wx0    = (f16*)carve((size_t)NG * 256 * 2);
    f16*   Wh0    = (f16*)carve((size_t)NG * 512 * 2);
    f16*   Wx1    = (f16*)carve((size_t)NG * 512 * 2);
    f16*   Wh1    = (f16*)carve((size_t)NG * 512 * 2);
    float* bias0c = (float*)carve(NG * 4);
    float* bias1c = (float*)carve(NG * 4);
    u64*   ring0  = (u64*)carve((size_t)4 * 8 * 2048 * 8);        // 512 KB
    u64*   ring1  = (u64*)carve((size_t)4 * 8 * 2048 * 8);
    u64*   d0r    = (u64*)carve((size_t)DSLOT * 8 * 2048 * 8);    // 8 MB
    u64*   z0r    = (u64*)carve((size_t)ZSLOT * 49152 * 8);       // 12.6 MB
    u64*   z1r    = (u64*)carve((size_t)ZSLOT * 49152 * 8);       // 12.6 MB
    int*   zflag1 = (int*)carve((size_t)S_ * 4);
    f16*   h1out  = (f16*)carve((size_t)B_ * H_ * 2);

    hipMemsetAsync(ring0, 0, (size_t)4 * 8 * 2048 * 8, stream);
    hipMemsetAsync(ring1, 0, (size_t)4 * 8 * 2048 * 8, stream);
    hipMemsetAsync(d0r, 0, (size_t)DSLOT * 8 * 2048 * 8, stream);
    hipMemsetAsync(zflag1, 0, (size_t)S_ * 4, stream);

    k_embconv<<<(V_ * E_ / 4 + 255) / 256, 256, 0, stream>>>(emb, embh);
    k_packW<<<384, 256, 0, stream>>>(gw0, 768, 0,    giw0, Wx0, 256);
    k_packW<<<768, 256, 0, stream>>>(gw0, 768, 256,  ghw0, Wh0, 512);
    k_packW<<<768, 256, 0, stream>>>(gw1, 1024, 0,   giw1, Wx1, 512);
    k_packW<<<768, 256, 0, stream>>>(gw1, 1024, 512, ghw1, Wh1, 512);
    k_packBias<<<6, 256, 0, stream>>>(gb0, gib0, bias0c);
    k_packBias<<<6, 256, 0, stream>>>(gb1, gib1, bias1c);

    k_mega<<<400, 256, 0, stream>>>(Wx0, Wh0, Wx1, Wh1, bias0c, bias1c,
                                    ghb0, ghb1, tokens, embh,
                                    ring0, ring1, d0r, z0r, z1r, zflag1, h1out);
    k_final<<<1, 64, 0, stream>>>(h1out, fc_w, fc_b, (float*)d_out);
}

// Round 15
// 2777.980 us; speedup vs baseline: 1.8007x; 1.2844x over previous
//
#include <hip/hip_runtime.h>

typedef _Float16 f16;
typedef _Float16 f16x8 __attribute__((ext_vector_type(8)));
typedef float f32x4 __attribute__((ext_vector_type(4)));
typedef unsigned long long u64;

#define B_ 64
#define S_ 1024
#define E_ 256
#define H_ 512
#define NG 1536         // 3*H packed gate rows (r | z | n)
#define TCH 128         // timesteps per chunk
#define NCHUNK (S_/TCH)
#define ROWS_CH (TCH*B_)   // 8192
#define HS_LD 544       // 1088B rows: quad-bank = 4*bq + j4 -> all 32 lane-groups distinct

__device__ __forceinline__ float sigm(float x) { return 1.f / (1.f + __expf(-x)); }

#define ALOAD(p) __hip_atomic_load((p), __ATOMIC_RELAXED, __HIP_MEMORY_SCOPE_AGENT)
#define ASTORE(p, v) __hip_atomic_store((p), (v), __ATOMIC_RELAXED, __HIP_MEMORY_SCOPE_AGENT)

// ---------------- embedding gather -> fp16, rows ordered (t, b) ----------------
__global__ __launch_bounds__(256) void k_embed(const int* __restrict__ tok,
        const float* __restrict__ emb, f16* __restrict__ X, int t0) {
    int idx = blockIdx.x * 256 + threadIdx.x;     // ROWS_CH * (E_/4) units
    int r = idx >> 6;                             // chunk-local row
    int c4 = (idx & 63) << 2;
    int t = t0 + (r >> 6), b = r & 63;
    int tk = tok[b * S_ + t];
    float4 v = *reinterpret_cast<const float4*>(emb + (size_t)tk * E_ + c4);
    union { f16 h[4]; u64 u; } w;
    w.h[0] = (f16)v.x; w.h[1] = (f16)v.y; w.h[2] = (f16)v.z; w.h[3] = (f16)v.w;
    *reinterpret_cast<u64*>(X + (size_t)r * E_ + c4) = w.u;
}

// ------------- pack [gate_w slice ; gi_or_gh_w] into fp16 [1536][KK] -------------
__global__ __launch_bounds__(256) void k_packW(const float* __restrict__ gw, int ld, int off,
        const float* __restrict__ g2, f16* __restrict__ W, int KK) {
    int idx = blockIdx.x * 256 + threadIdx.x;
    int per = KK >> 2;
    if (idx >= NG * per) return;
    int row = idx / per;
    int c4 = (idx % per) << 2;
    const float* src = (row < 1024) ? gw + (size_t)row * ld + off + c4
                                    : g2 + (size_t)(row - 1024) * KK + c4;
    float4 v = *reinterpret_cast<const float4*>(src);
    union { f16 h[4]; u64 u; } w;
    w.h[0] = (f16)v.x; w.h[1] = (f16)v.y; w.h[2] = (f16)v.z; w.h[3] = (f16)v.w;
    *reinterpret_cast<u64*>(W + (size_t)row * KK + c4) = w.u;
}

__global__ __launch_bounds__(256) void k_packBias(const float* __restrict__ gb,
        const float* __restrict__ gib, float* __restrict__ bias) {
    int i = blockIdx.x * 256 + threadIdx.x;
    if (i < 1024) bias[i] = gb[i];
    else if (i < NG) bias[i] = gib[i - 1024];
}

// --------- GEMM: C[M,1536] = A[M,K] * Bm[1536,K]^T + bias ; fp16 in/out, fp32 acc ---------
__global__ __launch_bounds__(256) void k_gemm(const f16* __restrict__ A,
        const f16* __restrict__ Bm, const float* __restrict__ bias,
        f16* __restrict__ C, int K) {
    __shared__ f16 As[64][40];
    __shared__ f16 Bs[64][40];
    const int tid = threadIdx.x;
    const int m0 = blockIdx.y << 6, n0 = blockIdx.x << 6;
    const int w = tid >> 6, l = tid & 63;
    const int wr = (w >> 1) << 5, wc = (w & 1) << 5;
    const int srow = tid >> 2, sc8 = (tid & 3) << 3;
    const int fr = l & 15, kl = (l >> 4) << 3;
    f32x4 acc[2][2] = {};
    for (int k0 = 0; k0 < K; k0 += 32) {
        *reinterpret_cast<f16x8*>(&As[srow][sc8]) =
            *reinterpret_cast<const f16x8*>(A + (size_t)(m0 + srow) * K + k0 + sc8);
        *reinterpret_cast<f16x8*>(&Bs[srow][sc8]) =
            *reinterpret_cast<const f16x8*>(Bm + (size_t)(n0 + srow) * K + k0 + sc8);
        __syncthreads();
        f16x8 a0 = *reinterpret_cast<const f16x8*>(&As[wr + fr][kl]);
        f16x8 a1 = *reinterpret_cast<const f16x8*>(&As[wr + 16 + fr][kl]);
        f16x8 b0 = *reinterpret_cast<const f16x8*>(&Bs[wc + fr][kl]);
        f16x8 b1 = *reinterpret_cast<const f16x8*>(&Bs[wc + 16 + fr][kl]);
        acc[0][0] = __builtin_amdgcn_mfma_f32_16x16x32_f16(a0, b0, acc[0][0], 0, 0, 0);
        acc[0][1] = __builtin_amdgcn_mfma_f32_16x16x32_f16(a0, b1, acc[0][1], 0, 0, 0);
        acc[1][0] = __builtin_amdgcn_mfma_f32_16x16x32_f16(a1, b0, acc[1][0], 0, 0, 0);
        acc[1][1] = __builtin_amdgcn_mfma_f32_16x16x32_f16(a1, b1, acc[1][1], 0, 0, 0);
        __syncthreads();
    }
    for (int fm = 0; fm < 2; ++fm)
        for (int fn = 0; fn < 2; ++fn) {
            int col = n0 + wc + (fn << 4) + fr;
            float bv = bias[col];
            for (int j = 0; j < 4; ++j) {
                int rowg = m0 + wr + (fm << 4) + ((l >> 4) << 2) + j;
                C[(size_t)rowg * NG + col] = (f16)(acc[fm][fn][j] + bv);
            }
        }
}

// --------------------------- persistent GRU recurrence, MFMA, tag-granule sync ---------------------------
// R9 structure verbatim, ONE isolated change: the stage block's chained per-granule
// retry is replaced by a miss-mask BATCHED retry (re-issue all stale granules per
// round -> ~1 LLC latency per round instead of up to 8 chained).
__global__ __launch_bounds__(256, 1) void k_recur4(
        const f16* __restrict__ Wh0p, const f16* __restrict__ Wh1p,
        const f16* __restrict__ Z0, const f16* __restrict__ Z1,
        const float* __restrict__ ghb0, const float* __restrict__ ghb1,
        u64* ring0, u64* ring1, f16* __restrict__ H0out, f16* __restrict__ h1out,
        int t00, int n0, int t01, int n1) {
    __shared__ __align__(16) f16 HS[8][HS_LD];    // staged h(s), plain row-major
    __shared__ __align__(16) f16 hx[8][40];       // gathered h_next (bank-spread)
    const int blk = blockIdx.x;
    const int c = blk & 7;
    const int l = (blk >> 3) & 1;
    const int gg = blk >> 4;                      // 0..15
    const int nsteps = l ? n1 : n0;
    if (nsteps <= 0) return;
    const int t0 = l ? t01 : t00;
    const f16* __restrict__ Wh = l ? Wh1p : Wh0p;
    const f16* __restrict__ Z  = l ? Z1 : Z0;
    const float* __restrict__ ghb = l ? ghb1 : ghb0;
    u64* ring = l ? ring1 : ring0;                // [4 slots][8 clusters][2048 granules]

    const int i0 = gg << 5;                       // WG's first output
    const int tid = threadIdx.x;
    const int w = tid >> 6;                       // wave -> outputs i0+8w..+8w+7
    const int lane = tid & 63;
    const int colb = lane & 15;                   // C/D col (batch slot; 8-15 dup)
    const int bq = lane & 7;                      // real batch within cluster
    const int j4 = lane >> 4;                     // k-octet for A/B frags; out-group for C/D
    const int rrow = lane & 15;
    const int ol = rrow >> 2, gate = rrow & 3;    // A-row decode: row = ol*4 + gate (3=pad)

    // ---- preload recurrent weights into registers (constant all steps) ----
    f16x8 wA[2][16];
    #pragma unroll
    for (int tl = 0; tl < 2; ++tl) {
        const int out = i0 + (w << 3) + (tl << 2) + ol;
        #pragma unroll
        for (int t = 0; t < 16; ++t) {
            f16x8 v{};
            if (gate < 3)
                v = *reinterpret_cast<const f16x8*>(
                        Wh + ((size_t)(gate * H_ + out)) * H_ + (t << 5) + (j4 << 3));
            wA[tl][t] = v;
        }
    }
    const int outA = i0 + (w << 3) + j4;          // tile 0 gate-math output
    const int outB = outA + 4;                    // tile 1
    const float gbA = ghb[outA], gbB = ghb[outB];

    for (int sl = 0; sl < nsteps; ++sl) {
        const int s = t0 + sl;
        // ---- Z prefetch (independent of h; hides under stage retry) ----
        const size_t zrow = ((size_t)sl * 64 + (c << 3) + bq) * NG;
        float zrA = (float)Z[zrow + outA];
        float zzA = (float)Z[zrow + H_ + outA];
        float znA = (float)Z[zrow + 2 * H_ + outA];
        float zrB = (float)Z[zrow + outB];
        float zzB = (float)Z[zrow + H_ + outB];
        float znB = (float)Z[zrow + 2 * H_ + outB];
        // ---- stage h(s): 8 tagged granules/thread, BATCHED miss-mask retry ----
        {
            const u64* src = ring + ((size_t)(s & 3) * 8 + c) * 2048;
            u64 g[8];
            #pragma unroll
            for (int i = 0; i < 8; ++i) g[i] = ALOAD(src + (i << 8) + tid);
            unsigned miss = 0;
            #pragma unroll
            for (int i = 0; i < 8; ++i) {
                if ((unsigned)(g[i] >> 32) == (unsigned)s) {
                    *reinterpret_cast<unsigned*>(
                        &HS[i][((tid >> 4) << 5) + ((tid & 15) << 1)]) = (unsigned)g[i];
                } else miss |= 1u << i;
            }
            while (miss) {
                #pragma unroll
                for (int i = 0; i < 8; ++i)
                    if (miss & (1u << i)) g[i] = ALOAD(src + (i << 8) + tid);
                #pragma unroll
                for (int i = 0; i < 8; ++i)
                    if ((miss & (1u << i)) && (unsigned)(g[i] >> 32) == (unsigned)s) {
                        *reinterpret_cast<unsigned*>(
                            &HS[i][((tid >> 4) << 5) + ((tid & 15) << 1)]) = (unsigned)g[i];
                        miss &= ~(1u << i);
                    }
            }
        }
        __syncthreads();
        // ---- MFMA: 2 tiles x K=512 (16 k-steps), B-frag shared across tiles ----
        f32x4 a00{}, a01{}, a10{}, a11{};
        #pragma unroll
        for (int t = 0; t < 16; ++t) {
            f16x8 bf = *reinterpret_cast<const f16x8*>(&HS[bq][(t << 5) + (j4 << 3)]);
            if (t & 1) {
                a01 = __builtin_amdgcn_mfma_f32_16x16x32_f16(wA[0][t], bf, a01, 0, 0, 0);
                a11 = __builtin_amdgcn_mfma_f32_16x16x32_f16(wA[1][t], bf, a11, 0, 0, 0);
            } else {
                a00 = __builtin_amdgcn_mfma_f32_16x16x32_f16(wA[0][t], bf, a00, 0, 0, 0);
                a10 = __builtin_amdgcn_mfma_f32_16x16x32_f16(wA[1][t], bf, a10, 0, 0, 0);
            }
        }
        f32x4 dA = a00 + a01;                     // rows: outA {r, z, n_h, pad}
        f32x4 dB = a10 + a11;                     // rows: outB
        // ---- gate math, in-lane; only cols 0-7 real ----
        if (colb < 8) {
            float holdA = (float)HS[bq][outA];
            float holdB = (float)HS[bq][outB];
            float rA = sigm(zrA + dA[0]);
            float zA = sigm(zzA + dA[1]);
            float nA = tanhf(znA + rA * (dA[2] + gbA));
            float rB = sigm(zrB + dB[0]);
            float zB = sigm(zzB + dB[1]);
            float nB = tanhf(znB + rB * (dB[2] + gbB));
            hx[bq][(w << 3) + j4]     = (f16)((1.f - zA) * nA + zA * holdA);
            hx[bq][(w << 3) + 4 + j4] = (f16)((1.f - zB) * nB + zB * holdB);
        }
        __syncthreads();
        // ---- publish h(s+1) as tagged granules (no drain, no flags) ----
        if (tid < 128) {
            const int b = tid >> 4, d = tid & 15;
            unsigned dval = *reinterpret_cast<const unsigned*>(&hx[b][d << 1]);
            u64 gr = ((u64)(unsigned)(s + 1) << 32) | (u64)dval;
            ASTORE(ring + ((size_t)((s + 1) & 3) * 8 + c) * 2048
                        + ((size_t)b << 8) + (gg << 4) + d, gr);
            if (l == 0)
                *reinterpret_cast<unsigned*>(
                    &H0out[((size_t)sl * 64 + (c << 3) + b) * H_ + i0 + (d << 1)]) = dval;
            else if (s == S_ - 1)
                *reinterpret_cast<unsigned*>(
                    &h1out[((size_t)(c << 3) + b) * H_ + i0 + (d << 1)]) = dval;
        }
        __syncthreads();   // hx reuse guard for next step
    }
}

// ------------------------------- final head -------------------------------
__global__ __launch_bounds__(64) void k_final(const f16* __restrict__ h,
        const float* __restrict__ fcw, const float* __restrict__ fcb,
        float* __restrict__ out) {
    int b = threadIdx.x;
    float acc = fcb[0];
    for (int k = 0; k < H_; ++k) acc += (float)h[(size_t)b * H_ + k] * fcw[k];
    out[b] = sigm(acc);
}

extern "C" void kernel_launch(void* const* d_in, const int* in_sizes, int n_in,
                              void* d_out, int out_size, void* d_ws, size_t ws_size,
                              hipStream_t stream) {
    (void)in_sizes; (void)n_in; (void)out_size; (void)ws_size;
    const int*   tokens = (const int*)d_in[0];
    const float* emb  = (const float*)d_in[1];
    const float* fc_w = (const float*)d_in[2];
    const float* fc_b = (const float*)d_in[3];
    const float* gw0  = (const float*)d_in[4];
    const float* gb0  = (const float*)d_in[5];
    const float* giw0 = (const float*)d_in[6];
    const float* gib0 = (const float*)d_in[7];
    const float* ghw0 = (const float*)d_in[8];
    const float* ghb0 = (const float*)d_in[9];
    const float* gw1  = (const float*)d_in[10];
    const float* gb1  = (const float*)d_in[11];
    const float* giw1 = (const float*)d_in[12];
    const float* gib1 = (const float*)d_in[13];
    const float* ghw1 = (const float*)d_in[14];
    const float* ghb1 = (const float*)d_in[15];

    char* base = (char*)d_ws;
    size_t off = 0;
    auto carve = [&](size_t bytes) {
        char* p = base + off;
        off = (off + bytes + 255) & ~(size_t)255;
        return p;
    };
    f16*   Wx0   = (f16*)carve((size_t)NG * 256 * 2);
    f16*   Wh0   = (f16*)carve((size_t)NG * 512 * 2);
    f16*   Wx1   = (f16*)carve((size_t)NG * 512 * 2);
    f16*   Wh1   = (f16*)carve((size_t)NG * 512 * 2);
    float* bias0 = (float*)carve(NG * 4);
    float* bias1 = (float*)carve(NG * 4);
    u64*   ring0 = (u64*)carve((size_t)4 * 8 * 2048 * 8);     // 512 KB
    u64*   ring1 = (u64*)carve((size_t)4 * 8 * 2048 * 8);     // 512 KB
    f16*   h1out = (f16*)carve((size_t)B_ * H_ * 2);
    f16*   Xc    = (f16*)carve((size_t)ROWS_CH * 256 * 2);
    f16*   Zc0   = (f16*)carve((size_t)ROWS_CH * NG * 2);
    f16*   H0c   = (f16*)carve((size_t)ROWS_CH * 512 * 2);
    f16*   Zc1   = (f16*)carve((size_t)ROWS_CH * NG * 2);

    hipMemsetAsync(ring0, 0, (size_t)4 * 8 * 2048 * 8, stream);
    hipMemsetAsync(ring1, 0, (size_t)4 * 8 * 2048 * 8, stream);

    k_packW<<<384, 256, 0, stream>>>(gw0, 768, 0,    giw0, Wx0, 256);
    k_packW<<<768, 256, 0, stream>>>(gw0, 768, 256,  ghw0, Wh0, 512);
    k_packW<<<768, 256, 0, stream>>>(gw1, 1024, 0,   giw1, Wx1, 512);
    k_packW<<<768, 256, 0, stream>>>(gw1, 1024, 512, ghw1, Wh1, 512);
    k_packBias<<<6, 256, 0, stream>>>(gb0, gib0, bias0);
    k_packBias<<<6, 256, 0, stream>>>(gb1, gib1, bias1);

    dim3 gemmGrid(NG / 64, ROWS_CH / 64);   // (24, 128)
    for (int ch = 0; ch < NCHUNK; ++ch) {
        int t0 = ch * TCH;
        k_embed<<<ROWS_CH * 64 / 256, 256, 0, stream>>>(tokens, emb, Xc, t0);
        k_gemm<<<gemmGrid, 256, 0, stream>>>(Xc, Wx0, bias0, Zc0, 256);
        // L0 of chunk ch runs concurrently with L1 of chunk ch-1
        k_recur4<<<256, 256, 0, stream>>>(Wh0, Wh1, Zc0, Zc1, ghb0, ghb1,
                                          ring0, ring1, H0c, h1out,
                                          t0, TCH, t0 - TCH, ch ? TCH : 0);
        k_gemm<<<gemmGrid, 256, 0, stream>>>(H0c, Wx1, bias1, Zc1, 512);
    }
    // drain: last chunk of layer 1
    k_recur4<<<256, 256, 0, stream>>>(Wh0, Wh1, Zc0, Zc1, ghb0, ghb1,
                                      ring0, ring1, H0c, h1out,
                                      0, 0, (NCHUNK - 1) * TCH, TCH);
    k_final<<<1, 64, 0, stream>>>(h1out, fc_w, fc_b, (float*)d_out);
}